// Round 2
// baseline (361.586 us; speedup 1.0000x reference)
//
#include <hip/hip_runtime.h>
#include <math.h>

#define TLEN   8192
#define BROWS  4096
#define NT     256
#define TILE   2048
#define NTILES (TLEN / TILE)
#define GAMMA  0.99f
#define EPSN   1e-9

typedef float f4 __attribute__((ext_vector_type(4)));

// ---------------------------------------------------------------------------
// K1: one row per block, whole row resident in registers, SINGLE barrier.
//
// Round-1 lesson [HIP-compiler]: hipcc drains vmcnt(0) before every s_barrier,
// so any per-tile __syncthreads() kills register-prefetch overlap and exposes
// the full ~900cy HBM latency once per tile, barrier-convoyed. Fix: no barrier
// in the data path. Thread t owns 4 runs of 8 elements (run k = elements
// [2048k + 8t, 2048k + 8t + 8), same 32B-lane-stride float4 pattern as
// round 1). All 16 loads issue up front (16KB/wave in flight); local suffix
// scans + 4 per-tile wave suffix scans happen in registers; ONE barrier
// publishes the 16 (tile,wave) affine composites to LDS; a predicated
// 16-entry compose loop then yields every run's incoming carry.
// ---------------------------------------------------------------------------
__global__ __launch_bounds__(NT) void er_scan(const float* __restrict__ rew,
                                              const float* __restrict__ don,
                                              float* __restrict__ out,
                                              double* __restrict__ rowSum,
                                              float* __restrict__ rowInv) {
  __shared__ float  sAl[16], sPl[16];   // m = 4*tile + wave
  __shared__ double red[8];

  const int row  = blockIdx.x;
  const int tid  = threadIdx.x;
  const int lane = tid & 63;
  const int wv   = tid >> 6;
  const size_t rbase = (size_t)row * TLEN;

  const f4* gr = (const f4*)(rew + rbase);
  const f4* gd = (const f4*)(don + rbase);

  // --- issue ALL loads up front: 16 x dwordx4 per thread, no barrier ---
  f4 R[8], D[8];
#pragma unroll
  for (int k = 0; k < NTILES; ++k) {
    const int f = k * (TILE / 4) + 2 * tid;
    R[2 * k]     = gr[f];
    R[2 * k + 1] = gr[f + 1];
    D[2 * k]     = gd[f];
    D[2 * k + 1] = gd[f + 1];
  }

  // --- unpack; cv = gamma*(1-done) ---
  float rv[32], cv[32];
#pragma unroll
  for (int k = 0; k < NTILES; ++k) {
    const f4 r0 = R[2 * k], r1 = R[2 * k + 1];
    const f4 d0 = D[2 * k], d1 = D[2 * k + 1];
    rv[8 * k + 0] = r0.x; rv[8 * k + 1] = r0.y; rv[8 * k + 2] = r0.z; rv[8 * k + 3] = r0.w;
    rv[8 * k + 4] = r1.x; rv[8 * k + 5] = r1.y; rv[8 * k + 6] = r1.z; rv[8 * k + 7] = r1.w;
    cv[8 * k + 0] = fmaf(-GAMMA, d0.x, GAMMA);
    cv[8 * k + 1] = fmaf(-GAMMA, d0.y, GAMMA);
    cv[8 * k + 2] = fmaf(-GAMMA, d0.z, GAMMA);
    cv[8 * k + 3] = fmaf(-GAMMA, d0.w, GAMMA);
    cv[8 * k + 4] = fmaf(-GAMMA, d1.x, GAMMA);
    cv[8 * k + 5] = fmaf(-GAMMA, d1.y, GAMMA);
    cv[8 * k + 6] = fmaf(-GAMMA, d1.z, GAMMA);
    cv[8 * k + 7] = fmaf(-GAMMA, d1.w, GAMMA);
  }

  // --- local suffix scan of affine maps per 8-element run ---
  // after this: rv[i] = A_{[i, run end)}, cv[i] = P_{[i, run end)}
#pragma unroll
  for (int k = 0; k < NTILES; ++k) {
    float A = 0.f, P = 1.f;
#pragma unroll
    for (int j = 7; j >= 0; --j) {
      const int i = 8 * k + j;
      A = fmaf(cv[i], A, rv[i]);
      P *= cv[i];
      rv[i] = A;
      cv[i] = P;
    }
  }

  // --- per-tile wave inclusive suffix scan of run composites ---
  float eA[4], eP[4];
#pragma unroll
  for (int k = 0; k < NTILES; ++k) {
    float sA = rv[8 * k], sP = cv[8 * k];
#pragma unroll
    for (int d = 1; d < 64; d <<= 1) {
      const float uA = __shfl_down(sA, d);
      const float uP = __shfl_down(sP, d);
      if (lane + d < 64) { sA = fmaf(sP, uA, sA); sP *= uP; }
    }
    if (lane == 0) { sAl[4 * k + wv] = sA; sPl[4 * k + wv] = sP; }
    // exclusive (lanes above) within wave for this tile
    const float xA = __shfl_down(sA, 1);
    const float xP = __shfl_down(sP, 1);
    eA[k] = (lane == 63) ? 0.f : xA;
    eP[k] = (lane == 63) ? 1.f : xP;
  }

  __syncthreads();   // the ONLY barrier in the data path

  // --- compose carries: process entries m=15..0 (rightmost first). ---
  // wc[k] = composite of all entries strictly right of (tile k, this wave),
  // applied to 0 (row-initial carry).
  float wc[4];
  float x = 0.f;
#pragma unroll
  for (int m = 15; m >= 0; --m) {
    if ((m & 3) == wv) wc[m >> 2] = x;
    x = fmaf(sPl[m], x, sAl[m]);
  }

  // --- fixup, store, stats ---
  double accS = 0.0, accQ = 0.0;
#pragma unroll
  for (int k = 0; k < NTILES; ++k) {
    const float carry = fmaf(eP[k], wc[k], eA[k]);
    float fsum = 0.f, fsq = 0.f;
    float o[8];
#pragma unroll
    for (int j = 0; j < 8; ++j) {
      const float r = fmaf(cv[8 * k + j], carry, rv[8 * k + j]);
      o[j] = r;
      fsum += r;
      fsq  = fmaf(r, r, fsq);
    }
    f4* go = (f4*)(out + rbase + (size_t)k * TILE) + 2 * tid;
    f4 o0; o0.x = o[0]; o0.y = o[1]; o0.z = o[2]; o0.w = o[3];
    f4 o1; o1.x = o[4]; o1.y = o[5]; o1.z = o[6]; o1.w = o[7];
    go[0] = o0;
    go[1] = o1;
    accS += (double)fsum;
    accQ += (double)fsq;
  }

  // --- block reduction (double) for row stats ---
  double ds = accS, dq = accQ;
#pragma unroll
  for (int d = 32; d >= 1; d >>= 1) {
    ds += __shfl_down(ds, d);
    dq += __shfl_down(dq, d);
  }
  if (lane == 0) { red[wv] = ds; red[4 + wv] = dq; }
  __syncthreads();
  if (tid == 0) {
    const double s = red[0] + red[1] + red[2] + red[3];
    const double q = red[4] + red[5] + red[6] + red[7];
    rowSum[row] = s;
    double var = (q - s * s / (double)TLEN) / (double)(TLEN - 1);
    if (var < 0.0) var = 0.0;
    rowInv[row] = (float)(1.0 / (sqrt(var) + EPSN));
  }
}

// ---------------------------------------------------------------------------
// K2: reduce 4096 per-row sums -> global mean (single block)
// ---------------------------------------------------------------------------
__global__ __launch_bounds__(256) void er_mean(const double* __restrict__ rowSum,
                                               float* __restrict__ meanPtr) {
  const int tid = threadIdx.x;
  double s = 0.0;
  for (int i = tid; i < BROWS; i += 256) s += rowSum[i];
#pragma unroll
  for (int d = 32; d >= 1; d >>= 1) s += __shfl_down(s, d);
  __shared__ double red[4];
  const int lane = tid & 63, wv = tid >> 6;
  if (lane == 0) red[wv] = s;
  __syncthreads();
  if (tid == 0) {
    const double t = red[0] + red[1] + red[2] + red[3];
    *meanPtr = (float)(t / ((double)BROWS * (double)TLEN));
  }
}

// ---------------------------------------------------------------------------
// K3: out = (out - mean) * invstd[row]; grid-stride, float4, plain stores
// (nontemporal stores reverted: round-1 total regressed ~9us with them).
// ---------------------------------------------------------------------------
#define K3_BLOCKS 2048
__global__ __launch_bounds__(256) void er_norm(float* __restrict__ out,
                                               const float* __restrict__ rowInv,
                                               const float* __restrict__ meanPtr) {
  const float mean = *meanPtr;
  const unsigned total4 = (unsigned)BROWS * (TLEN / 4);
  const unsigned stride = K3_BLOCKS * 256;
  f4* o4 = (f4*)out;
  for (unsigned i = blockIdx.x * 256 + threadIdx.x; i < total4; i += stride) {
    const int row = (int)(i >> 11);          // TLEN/4 = 2048 float4 per row
    const float inv = rowInv[row];
    f4 v = o4[i];
    v.x = (v.x - mean) * inv;
    v.y = (v.y - mean) * inv;
    v.z = (v.z - mean) * inv;
    v.w = (v.w - mean) * inv;
    o4[i] = v;
  }
}

extern "C" void kernel_launch(void* const* d_in, const int* in_sizes, int n_in,
                              void* d_out, int out_size, void* d_ws, size_t ws_size,
                              hipStream_t stream) {
  const float* rew = (const float*)d_in[0];
  const float* don = (const float*)d_in[1];
  float* out = (float*)d_out;

  double* rowSum  = (double*)d_ws;
  float*  rowInv  = (float*)((char*)d_ws + BROWS * 8);
  float*  meanPtr = (float*)((char*)d_ws + BROWS * 8 + BROWS * 4);

  er_scan<<<BROWS, NT, 0, stream>>>(rew, don, out, rowSum, rowInv);
  er_mean<<<1, 256, 0, stream>>>(rowSum, meanPtr);
  er_norm<<<K3_BLOCKS, 256, 0, stream>>>(out, rowInv, meanPtr);
}